// Round 6
// baseline (352.374 us; speedup 1.0000x reference)
//
#include <hip/hip_runtime.h>
#include <math.h>

// N=500k points, C=1000 cells, L=16 clusters, G=500 genes, NT=10000,
// K=224 heights, W=221 widths, spline levels (128,64,32).
//
// clustering one-hot => spline params depend only on (gene,cluster) pair
// (P=8000). Pipeline: [memset 40KB] -> [kB: per-block cid in LDS + scatter
// points into per-pair buckets + per-cluster sumexp] -> [k_pair: one wave per
// pair builds spline table in LDS via fused scans, evaluates bucket,
// last-done block reduces partials to the scalar output].

#define CAP 192       // bucket capacity (mean 62.5, max ~135)
static constexpr float  F_MBW = 1e-3f;
static constexpr float  F_MBH = 1e-3f;
static constexpr double D_HL2PI = 0.918938533204672741780329736406;

// ws layout (bytes):
//      0: double dpart[16*8]  (per-cluster sumexp, one cache line apart)
//   4096: int done            (completion ticket for last-block reduce)
//   8192: int cnt[P]
//  40960: float partA[P]      <- memset covers [0, 40960)
//  73728: float partB[P]
// 131072: float xs[P*CAP]     (~6.1 MB)

// ---------------- kB: cid-in-LDS scatter + per-cluster sumexp ----------------
__global__ void __launch_bounds__(256)
kB(const float* __restrict__ coords, const int* __restrict__ lgi,
   const int* __restrict__ lcg, const float* __restrict__ clustering,
   const float* __restrict__ bb, const float* __restrict__ dbw,
   int* __restrict__ cnt, float* __restrict__ xs, double* __restrict__ dpart,
   int N, int C, int G, int L, int NT, int SCAT) {
  int bid = blockIdx.x;
  if (bid < SCAT) {
    // per-block cluster-id table (clustering is 64KB, L2-resident)
    __shared__ unsigned char s_cid[1024];
    for (int c = threadIdx.x; c < C; c += 256) {
      const float* row = clustering + (size_t)c * L;
      int best = 0; float bv = row[0];
      for (int l = 1; l < L; ++l) { float v = row[l]; if (v > bv) { bv = v; best = l; } }
      s_cid[c] = (unsigned char)best;
    }
    __syncthreads();
    int n0 = (bid * 256 + threadIdx.x) * 2;
    #pragma unroll
    for (int q = 0; q < 2; ++q) {
      int n = n0 + q;
      if (n < N) {
        int pair = lgi[n] * L + (int)s_cid[lcg[n] / G];
        int pos = atomicAdd(&cnt[pair], 1);
        if (pos < CAP) xs[(size_t)pair * CAP + pos] = coords[n];
      }
    }
  } else {
    // per-cluster sum_t bb[t]*exp(dbw[t,l]); values in [8e-6,1.3] -> no max shift
    int g = (bid - SCAT) * 256 + threadIdx.x;
    float s[16];
    #pragma unroll
    for (int l = 0; l < 16; ++l) s[l] = 0.f;
    if (g < NT) {
      float b = bb[g];
      const float4* row = (const float4*)(dbw + (size_t)g * 16);
      #pragma unroll
      for (int q = 0; q < 4; ++q) {
        float4 v = row[q];
        s[4 * q + 0] = b * expf(v.x); s[4 * q + 1] = b * expf(v.y);
        s[4 * q + 2] = b * expf(v.z); s[4 * q + 3] = b * expf(v.w);
      }
    }
    __shared__ float partl[4][16];
    int lane = threadIdx.x & 63, wv = threadIdx.x >> 6;
    #pragma unroll
    for (int l = 0; l < 16; ++l) {
      float v = s[l];
      for (int off = 32; off; off >>= 1) v += __shfl_xor(v, off);
      if (lane == 0) partl[wv][l] = v;
    }
    __syncthreads();
    if (threadIdx.x < 16) {
      float t = partl[0][threadIdx.x] + partl[1][threadIdx.x]
              + partl[2][threadIdx.x] + partl[3][threadIdx.x];
      atomicAdd(&dpart[threadIdx.x * 8], (double)t);
    }
  }
}

// ---------------- wave (64-lane) inclusive scan ----------------
static __device__ __forceinline__ float wscan(float v, int lane) {
  #pragma unroll
  for (int off = 1; off < 64; off <<= 1) {
    float u = __shfl_up(v, off, 64);
    if (lane >= off) v += u;
  }
  return v;
}

// ---------------- per-pair (ONE WAVE): build table, evaluate, last reduces ----------------
__global__ void __launch_bounds__(64)
k_pair(const float* __restrict__ uh, const float* __restrict__ uw,
       const float* __restrict__ dhw, const int* __restrict__ genes_oi,
       const float* __restrict__ xs, const int* __restrict__ cnt,
       const float* __restrict__ bb, const float* __restrict__ dbw,
       const double* __restrict__ dpart,
       float* __restrict__ partA, float* __restrict__ partB,
       int* __restrict__ done, float* __restrict__ out,
       int L, int K, int W, int NT, int P, long long M12) {
  int p = blockIdx.x;            // g*L + l
  int g = p / L;
  int cl = p - g * L;
  int gg = genes_oi[g];
  const float* uhg  = uh + (size_t)gg * K;
  const float* uwg  = uw + (size_t)gg * W;
  const float* drow = dhw + ((size_t)gg * L + cl) * K;
  int t = threadIdx.x;

  __shared__ float4 tab[224];   // per level: {loc, cdf, h, pad} x nbp1
  __shared__ int    grd[224];   // per level: uniform-grid cell -> start bin
  __shared__ float  s_h[128];
  __shared__ int    s_last;

  const float cw128 = 1.0f - F_MBW * 127.0f;
  const float chh   = 1.0f - F_MBH;
  float d2;

  // ======== level 0: nbp1=128, 2 elements per lane ========
  {
    int i0 = 2 * t, i1 = 2 * t + 1;
    float2 dv = *(const float2*)(drow + i0);
    float2 uv = *(const float2*)(uhg + i0);
    d2 = dv.x * dv.x + dv.y * dv.y;
    float hexp0 = expf(uv.x + dv.x), hexp1 = expf(uv.y + dv.y);
    s_h[i0] = hexp0; s_h[i1] = hexp1;
    float ew0 = expf(uwg[i0]);                    // i0 <= 126 < 127 always
    float ew1 = (i1 < 127) ? expf(uwg[i1]) : 0.f;
    float ps = wscan(ew0 + ew1, t);
    float wsum = __shfl(ps, 63);
    float incl0 = ps - ew1;
    float excl0 = incl0 - ew0, excl1 = incl0;
    float rw = cw128 / wsum;
    float width0 = F_MBW + rw * ew0;
    float width1 = F_MBW + rw * ew1;
    float loc0 = F_MBW * (float)i0 + rw * excl0;
    float loc1 = F_MBW * (float)i1 + rw * excl1;
    __syncthreads();
    float hn = (i1 < 127) ? s_h[i1 + 1] : 0.f;
    float at0 = 0.5f * (hexp0 + hexp1) * width0;
    float at1 = (i1 < 127) ? 0.5f * (hexp1 + hn) * width1 : 0.f;
    float pa = wscan(at0 + at1, t);
    float area = __shfl(pa, 63);
    float aincl0 = pa - at1;
    float aexcl0 = aincl0 - at0, aexcl1 = aincl0;
    float ra = chh / area;
    float h0 = F_MBH + ra * hexp0, h1 = F_MBH + ra * hexp1;
    float cdf0 = F_MBH * loc0 + ra * aexcl0;
    float cdf1 = F_MBH * loc1 + ra * aexcl1;
    if (i1 == 127) { loc1 = 1.0f; cdf1 = 1.0f; }
    tab[i0] = make_float4(loc0, cdf0, h0, 0.f);
    tab[i1] = make_float4(loc1, cdf1, h1, 0.f);
  }

  // ======== levels 1,2: one element per lane ========
  int ho = 128, wo = 127, tb = 128;
  #pragma unroll
  for (int lev = 1; lev < 3; ++lev) {
    const int nbp1 = (lev == 1) ? 64 : 32;
    const int nb = nbp1 - 1;
    const float cwl = 1.0f - F_MBW * (float)nb;
    float dvx = (t < nbp1) ? drow[ho + t] : 0.f;
    d2 += dvx * dvx;
    float hexp = (t < nbp1) ? expf(uhg[ho + t] + dvx) : 0.f;
    __syncthreads();                 // previous level's s_h reads done
    s_h[t] = hexp;
    float ew = (t < nb) ? expf(uwg[wo + t]) : 0.f;
    float ips = wscan(ew, t);
    float wsum = __shfl(ips, nb - 1);
    float excl = ips - ew;
    float rw = cwl / wsum;
    float width = F_MBW + rw * ew;
    float loc = F_MBW * (float)t + rw * excl;
    __syncthreads();
    float hn = (t + 1 < nbp1) ? s_h[t + 1] : 0.f;
    float at = (t < nb) ? 0.5f * (hexp + hn) * width : 0.f;
    float ipa = wscan(at, t);
    float area = __shfl(ipa, nb - 1);
    float aexcl = ipa - at;
    float ra = chh / area;
    float h = F_MBH + ra * hexp;
    float cdf = F_MBH * loc + ra * aexcl;
    if (t == nb) { loc = 1.0f; cdf = 1.0f; }
    if (t < nbp1) tab[tb + t] = make_float4(loc, cdf, h, 0.f);
    ho += nbp1; wo += nb; tb += nbp1;
  }
  __syncthreads();

  // ======== uniform-grid accelerator ========
  {
    #pragma unroll
    for (int q = 0; q < 2; ++q) {     // level 0: two targets per lane
      int j = 2 * t + q;
      float target = (float)j * (1.0f / 128.0f);
      int lo = 0, hi = 128;
      #pragma unroll
      for (int it = 0; it < 7; ++it) {
        int mid = (lo + hi) >> 1;
        if (tab[mid].x <= target) lo = mid; else hi = mid;
      }
      grd[j] = (lo > 126) ? 126 : lo;
    }
    { // level 1
      float target = (float)t * (1.0f / 64.0f);
      int lo = 0, hi = 64;
      #pragma unroll
      for (int it = 0; it < 6; ++it) {
        int mid = (lo + hi) >> 1;
        if (tab[128 + mid].x <= target) lo = mid; else hi = mid;
      }
      grd[128 + t] = (lo > 62) ? 62 : lo;
    }
    if (t < 32) { // level 2
      float target = (float)t * (1.0f / 32.0f);
      int lo = 0, hi = 32;
      #pragma unroll
      for (int it = 0; it < 5; ++it) {
        int mid = (lo + hi) >> 1;
        if (tab[192 + mid].x <= target) lo = mid; else hi = mid;
      }
      grd[192 + t] = (lo > 30) ? 30 : lo;
    }
  }
  __syncthreads();

  // ======== evaluate bucket ========
  int m = cnt[p]; if (m > CAP) m = CAP;
  float lad_sum = 0.f;
  for (int i = t; i < m; i += 64) {
    float x = xs[(size_t)p * CAP + i];
    float lad = 0.f;
    int b2 = 0;
    #pragma unroll
    for (int lev = 0; lev < 3; ++lev) {
      const int nbp1 = (lev == 0) ? 128 : (lev == 1) ? 64 : 32;
      int j = (int)(x * (float)nbp1);
      j = (j > nbp1 - 1) ? (nbp1 - 1) : j;
      int idx = grd[b2 + j];
      while (idx > 0 && tab[b2 + idx].x > x) --idx;                 // fp boundary guard
      while (idx < nbp1 - 2 && tab[b2 + idx + 1].x <= x) ++idx;     // advance (<=1 typ.)
      float4 a = tab[b2 + idx];
      float4 b = tab[b2 + idx + 1];
      float w = b.x - a.x;
      float alpha = (x - a.x) / w;
      float dh = b.z - a.z;
      float outv = (0.5f * dh * alpha + a.z) * (w * alpha) + a.y;
      x = fminf(fmaxf(outv, 0.f), 1.f);
      lad += logf(alpha * dh + a.z);
      b2 += nbp1;
    }
    lad_sum += lad;
  }
  // wave-only reductions
  #pragma unroll
  for (int off = 32; off; off >>= 1) {
    lad_sum += __shfl_xor(lad_sum, off);
    d2      += __shfl_xor(d2, off);
  }
  if (t == 0) {
    float dv = dbw[(size_t)gg * L + cl];
    float rc = logf(bb[gg]) + dv - logf((float)dpart[cl * 8]) + logf((float)NT);
    partA[p] = lad_sum + (float)m * rc;
    partB[p] = d2 + dv * dv;
  }

  // ======== last-done block reduces all partials ========
  __threadfence();                 // release: partA/partB visible device-wide
  if (t == 0) {
    int ticket = atomicAdd(done, 1);
    s_last = (ticket == P - 1) ? 1 : 0;
  }
  __syncthreads();
  if (s_last) {
    __threadfence();               // acquire: invalidate stale L1
    double sa = 0.0, sb = 0.0;
    for (int i = t; i < P; i += 64) {
      sa += (double)partA[i];
      sb += (double)partB[i];
    }
    #pragma unroll
    for (int off = 32; off; off >>= 1) {
      sa += __shfl_xor(sa, off);
      sb += __shfl_xor(sb, off);
    }
    if (t == 0)
      out[0] = (float)(-sa + 0.5 * sb + (double)M12 * D_HL2PI);
  }
}

extern "C" void kernel_launch(void* const* d_in, const int* in_sizes, int n_in,
                              void* d_out, int out_size, void* d_ws, size_t ws_size,
                              hipStream_t stream) {
  const float* coords     = (const float*)d_in[0];
  const float* clustering = (const float*)d_in[1];
  const float* dhw        = (const float*)d_in[2];
  const float* dbw        = (const float*)d_in[3];
  const float* uh         = (const float*)d_in[4];
  const float* uw         = (const float*)d_in[5];
  const float* bb         = (const float*)d_in[6];
  const int*   genes_oi   = (const int*)d_in[7];
  const int*   lgi        = (const int*)d_in[8];
  const int*   lcg        = (const int*)d_in[9];

  int N  = in_sizes[0];
  int NT = in_sizes[6];
  int L  = in_sizes[3] / NT;   // 16
  int C  = in_sizes[1] / L;    // 1000
  int K  = in_sizes[4] / NT;   // 224
  int W  = in_sizes[5] / NT;   // 221
  int G  = in_sizes[7];        // 500
  int P  = G * L;              // 8000

  char* ws = (char*)d_ws;
  double* dpart = (double*)ws;
  int*    done  = (int*)(ws + 4096);
  int*    cnt   = (int*)(ws + 8192);
  float*  partA = (float*)(ws + 40960);
  float*  partB = (float*)(ws + 73728);
  float*  xs    = (float*)(ws + 131072);

  int SCAT = (N + 511) / 512;
  int LSEB = (NT + 255) / 256;

  hipMemsetAsync(ws, 0, 40960, stream);   // dpart + done + cnt
  hipLaunchKernelGGL(kB, dim3(SCAT + LSEB), dim3(256), 0, stream,
                     coords, lgi, lcg, clustering, bb, dbw, cnt, xs, dpart,
                     N, C, G, L, NT, SCAT);
  hipLaunchKernelGGL(k_pair, dim3(P), dim3(64), 0, stream,
                     uh, uw, dhw, genes_oi, xs, cnt, bb, dbw, dpart,
                     partA, partB, done, (float*)d_out,
                     L, K, W, NT, P, (long long)G * L * K + (long long)G * L);
}

// Round 7
// 82.538 us; speedup vs baseline: 4.2692x; 4.2692x over previous
//
#include <hip/hip_runtime.h>
#include <math.h>

// N=500k points, C=1000 cells, L=16 clusters, G=500 genes, NT=10000,
// K=224 heights, W=221 widths, spline levels (128,64,32).
//
// clustering one-hot => spline params depend only on (gene,cluster) pair
// (P=8000). Pipeline: [memset 40KB] -> [kB: per-block cid in LDS + scatter
// points into per-pair buckets + per-cluster sumexp] -> [k_pair: one wave per
// pair builds spline table in LDS (scalar arrays: bank-conflict-free random
// reads) via fused scans, evaluates bucket, stores per-pair partials] ->
// [k_final: single-block deterministic reduce].
// NOTE (round 6 lesson): do NOT fuse the final reduce via threadfence+ticket —
// 8000 same-address atomics serialize (~290us). Kernel boundary is cheaper.

#define CAP 192       // bucket capacity (mean 62.5, max ~135)
static constexpr float  F_MBW = 1e-3f;
static constexpr float  F_MBH = 1e-3f;
static constexpr double D_HL2PI = 0.918938533204672741780329736406;

// ws layout (bytes):
//      0: double dpart[16*8]  (per-cluster sumexp, one cache line apart)
//   8192: int cnt[P]
//  40960: float partA[P]      <- memset covers [0, 40960)
//  73728: float partB[P]
// 131072: float xs[P*CAP]     (~6.1 MB)

// ---------------- kB: cid-in-LDS scatter + per-cluster sumexp ----------------
__global__ void __launch_bounds__(256)
kB(const float* __restrict__ coords, const int* __restrict__ lgi,
   const int* __restrict__ lcg, const float* __restrict__ clustering,
   const float* __restrict__ bb, const float* __restrict__ dbw,
   int* __restrict__ cnt, float* __restrict__ xs, double* __restrict__ dpart,
   int N, int C, int G, int L, int NT, int SCAT) {
  int bid = blockIdx.x;
  if (bid < SCAT) {
    // per-block cluster-id table (clustering is 64KB, L2-resident)
    __shared__ unsigned char s_cid[1024];
    for (int c = threadIdx.x; c < C; c += 256) {
      const float* row = clustering + (size_t)c * L;
      int best = 0; float bv = row[0];
      for (int l = 1; l < L; ++l) { float v = row[l]; if (v > bv) { bv = v; best = l; } }
      s_cid[c] = (unsigned char)best;
    }
    __syncthreads();
    int n0 = (bid * 256 + threadIdx.x) * 2;
    #pragma unroll
    for (int q = 0; q < 2; ++q) {
      int n = n0 + q;
      if (n < N) {
        int pair = lgi[n] * L + (int)s_cid[lcg[n] / G];
        int pos = atomicAdd(&cnt[pair], 1);
        if (pos < CAP) xs[(size_t)pair * CAP + pos] = coords[n];
      }
    }
  } else {
    // per-cluster sum_t bb[t]*exp(dbw[t,l]); values in [8e-6,1.3] -> no max shift
    int g = (bid - SCAT) * 256 + threadIdx.x;
    float s[16];
    #pragma unroll
    for (int l = 0; l < 16; ++l) s[l] = 0.f;
    if (g < NT) {
      float b = bb[g];
      const float4* row = (const float4*)(dbw + (size_t)g * 16);
      #pragma unroll
      for (int q = 0; q < 4; ++q) {
        float4 v = row[q];
        s[4 * q + 0] = b * expf(v.x); s[4 * q + 1] = b * expf(v.y);
        s[4 * q + 2] = b * expf(v.z); s[4 * q + 3] = b * expf(v.w);
      }
    }
    __shared__ float partl[4][16];
    int lane = threadIdx.x & 63, wv = threadIdx.x >> 6;
    #pragma unroll
    for (int l = 0; l < 16; ++l) {
      float v = s[l];
      for (int off = 32; off; off >>= 1) v += __shfl_xor(v, off);
      if (lane == 0) partl[wv][l] = v;
    }
    __syncthreads();
    if (threadIdx.x < 16) {
      float t = partl[0][threadIdx.x] + partl[1][threadIdx.x]
              + partl[2][threadIdx.x] + partl[3][threadIdx.x];
      atomicAdd(&dpart[threadIdx.x * 8], (double)t);
    }
  }
}

// ---------------- wave (64-lane) inclusive scan ----------------
static __device__ __forceinline__ float wscan(float v, int lane) {
  #pragma unroll
  for (int off = 1; off < 64; off <<= 1) {
    float u = __shfl_up(v, off, 64);
    if (lane >= off) v += u;
  }
  return v;
}

// ---------------- per-pair (ONE WAVE): build table in LDS, evaluate ----------------
__global__ void __launch_bounds__(64)
k_pair(const float* __restrict__ uh, const float* __restrict__ uw,
       const float* __restrict__ dhw, const int* __restrict__ genes_oi,
       const float* __restrict__ xs, const int* __restrict__ cnt,
       const float* __restrict__ bb, const float* __restrict__ dbw,
       const double* __restrict__ dpart,
       float* __restrict__ partA, float* __restrict__ partB,
       int L, int K, int W, int NT) {
  int p = blockIdx.x;            // g*L + l
  int g = p / L;
  int cl = p - g * L;
  int gg = genes_oi[g];
  const float* uhg  = uh + (size_t)gg * K;
  const float* uwg  = uw + (size_t)gg * W;
  const float* drow = dhw + ((size_t)gg * L + cl) * K;
  int t = threadIdx.x;

  // scalar per-field arrays: random-idx 4B reads spread over all 32 banks
  __shared__ float s_loc[224];
  __shared__ float s_cdf[224];
  __shared__ float s_hh[224];
  __shared__ int   grd[224];     // uniform-grid cell -> start bin
  __shared__ float s_stg[128];   // hexp staging for neighbor access

  const float cw128 = 1.0f - F_MBW * 127.0f;
  const float chh   = 1.0f - F_MBH;
  float d2;

  // ======== level 0: nbp1=128, 2 elements per lane ========
  {
    int i0 = 2 * t, i1 = 2 * t + 1;
    float2 dv = *(const float2*)(drow + i0);
    float2 uv = *(const float2*)(uhg + i0);
    d2 = dv.x * dv.x + dv.y * dv.y;
    float hexp0 = expf(uv.x + dv.x), hexp1 = expf(uv.y + dv.y);
    s_stg[i0] = hexp0; s_stg[i1] = hexp1;
    float ew0 = expf(uwg[i0]);                    // i0 <= 126 < 127 always
    float ew1 = (i1 < 127) ? expf(uwg[i1]) : 0.f;
    float ps = wscan(ew0 + ew1, t);
    float wsum = __shfl(ps, 63);
    float incl0 = ps - ew1;
    float excl0 = incl0 - ew0, excl1 = incl0;
    float rw = cw128 / wsum;
    float width0 = F_MBW + rw * ew0;
    float width1 = F_MBW + rw * ew1;
    float loc0 = F_MBW * (float)i0 + rw * excl0;
    float loc1 = F_MBW * (float)i1 + rw * excl1;
    __syncthreads();
    float hn = (i1 < 127) ? s_stg[i1 + 1] : 0.f;
    float at0 = 0.5f * (hexp0 + hexp1) * width0;
    float at1 = (i1 < 127) ? 0.5f * (hexp1 + hn) * width1 : 0.f;
    float pa = wscan(at0 + at1, t);
    float area = __shfl(pa, 63);
    float aincl0 = pa - at1;
    float aexcl0 = aincl0 - at0, aexcl1 = aincl0;
    float ra = chh / area;
    float h0 = F_MBH + ra * hexp0, h1 = F_MBH + ra * hexp1;
    float cdf0 = F_MBH * loc0 + ra * aexcl0;
    float cdf1 = F_MBH * loc1 + ra * aexcl1;
    if (i1 == 127) { loc1 = 1.0f; cdf1 = 1.0f; }
    s_loc[i0] = loc0; s_cdf[i0] = cdf0; s_hh[i0] = h0;
    s_loc[i1] = loc1; s_cdf[i1] = cdf1; s_hh[i1] = h1;
  }

  // ======== levels 1,2: one element per lane ========
  int ho = 128, wo = 127, tb = 128;
  #pragma unroll
  for (int lev = 1; lev < 3; ++lev) {
    const int nbp1 = (lev == 1) ? 64 : 32;
    const int nb = nbp1 - 1;
    const float cwl = 1.0f - F_MBW * (float)nb;
    float dvx = (t < nbp1) ? drow[ho + t] : 0.f;
    d2 += dvx * dvx;
    float hexp = (t < nbp1) ? expf(uhg[ho + t] + dvx) : 0.f;
    __syncthreads();                 // previous level's s_stg reads done
    s_stg[t] = hexp;
    float ew = (t < nb) ? expf(uwg[wo + t]) : 0.f;
    float ips = wscan(ew, t);
    float wsum = __shfl(ips, nb - 1);
    float excl = ips - ew;
    float rw = cwl / wsum;
    float width = F_MBW + rw * ew;
    float loc = F_MBW * (float)t + rw * excl;
    __syncthreads();
    float hn = (t + 1 < nbp1) ? s_stg[t + 1] : 0.f;
    float at = (t < nb) ? 0.5f * (hexp + hn) * width : 0.f;
    float ipa = wscan(at, t);
    float area = __shfl(ipa, nb - 1);
    float aexcl = ipa - at;
    float ra = chh / area;
    float h = F_MBH + ra * hexp;
    float cdf = F_MBH * loc + ra * aexcl;
    if (t == nb) { loc = 1.0f; cdf = 1.0f; }
    if (t < nbp1) { s_loc[tb + t] = loc; s_cdf[tb + t] = cdf; s_hh[tb + t] = h; }
    ho += nbp1; wo += nb; tb += nbp1;
  }
  __syncthreads();

  // ======== uniform-grid accelerator ========
  {
    #pragma unroll
    for (int q = 0; q < 2; ++q) {     // level 0: two targets per lane
      int j = 2 * t + q;
      float target = (float)j * (1.0f / 128.0f);
      int lo = 0, hi = 128;
      #pragma unroll
      for (int it = 0; it < 7; ++it) {
        int mid = (lo + hi) >> 1;
        if (s_loc[mid] <= target) lo = mid; else hi = mid;
      }
      grd[j] = (lo > 126) ? 126 : lo;
    }
    { // level 1
      float target = (float)t * (1.0f / 64.0f);
      int lo = 0, hi = 64;
      #pragma unroll
      for (int it = 0; it < 6; ++it) {
        int mid = (lo + hi) >> 1;
        if (s_loc[128 + mid] <= target) lo = mid; else hi = mid;
      }
      grd[128 + t] = (lo > 62) ? 62 : lo;
    }
    if (t < 32) { // level 2
      float target = (float)t * (1.0f / 32.0f);
      int lo = 0, hi = 32;
      #pragma unroll
      for (int it = 0; it < 5; ++it) {
        int mid = (lo + hi) >> 1;
        if (s_loc[192 + mid] <= target) lo = mid; else hi = mid;
      }
      grd[192 + t] = (lo > 30) ? 30 : lo;
    }
  }
  __syncthreads();

  // ======== evaluate bucket ========
  int m = cnt[p]; if (m > CAP) m = CAP;
  float lad_sum = 0.f;
  for (int i = t; i < m; i += 64) {
    float x = xs[(size_t)p * CAP + i];
    float lad = 0.f;
    int b2 = 0;
    #pragma unroll
    for (int lev = 0; lev < 3; ++lev) {
      const int nbp1 = (lev == 0) ? 128 : (lev == 1) ? 64 : 32;
      int j = (int)(x * (float)nbp1);
      j = (j > nbp1 - 1) ? (nbp1 - 1) : j;
      int idx = grd[b2 + j];
      while (idx > 0 && s_loc[b2 + idx] > x) --idx;                 // fp boundary guard
      while (idx < nbp1 - 2 && s_loc[b2 + idx + 1] <= x) ++idx;     // advance (<=1 typ.)
      float la = s_loc[b2 + idx];
      float w  = s_loc[b2 + idx + 1] - la;
      float cd = s_cdf[b2 + idx];
      float hl = s_hh[b2 + idx];
      float hr = s_hh[b2 + idx + 1];
      float alpha = (x - la) / w;
      float dh = hr - hl;
      float outv = (0.5f * dh * alpha + hl) * (w * alpha) + cd;
      x = fminf(fmaxf(outv, 0.f), 1.f);
      lad += logf(alpha * dh + hl);
      b2 += nbp1;
    }
    lad_sum += lad;
  }
  // wave-only reductions
  #pragma unroll
  for (int off = 32; off; off >>= 1) {
    lad_sum += __shfl_xor(lad_sum, off);
    d2      += __shfl_xor(d2, off);
  }
  if (t == 0) {
    float dv = dbw[(size_t)gg * L + cl];
    float rc = logf(bb[gg]) + dv - logf((float)dpart[cl * 8]) + logf((float)NT);
    partA[p] = lad_sum + (float)m * rc;
    partB[p] = d2 + dv * dv;
  }
}

// ---------------- final single-block deterministic reduce ----------------
__global__ void __launch_bounds__(256)
k_final(const float* __restrict__ partA, const float* __restrict__ partB,
        float* __restrict__ out, int P, long long M12) {
  int tid = threadIdx.x;
  double sa = 0.0, sb = 0.0;
  for (int i = tid; i < P; i += 256) { sa += (double)partA[i]; sb += (double)partB[i]; }
  __shared__ double rA[256], rB[256];
  rA[tid] = sa; rB[tid] = sb;
  __syncthreads();
  for (int off = 128; off > 0; off >>= 1) {
    if (tid < off) { rA[tid] += rA[tid + off]; rB[tid] += rB[tid + off]; }
    __syncthreads();
  }
  if (tid == 0)
    out[0] = (float)(-rA[0] + 0.5 * rB[0] + (double)M12 * D_HL2PI);
}

extern "C" void kernel_launch(void* const* d_in, const int* in_sizes, int n_in,
                              void* d_out, int out_size, void* d_ws, size_t ws_size,
                              hipStream_t stream) {
  const float* coords     = (const float*)d_in[0];
  const float* clustering = (const float*)d_in[1];
  const float* dhw        = (const float*)d_in[2];
  const float* dbw        = (const float*)d_in[3];
  const float* uh         = (const float*)d_in[4];
  const float* uw         = (const float*)d_in[5];
  const float* bb         = (const float*)d_in[6];
  const int*   genes_oi   = (const int*)d_in[7];
  const int*   lgi        = (const int*)d_in[8];
  const int*   lcg        = (const int*)d_in[9];

  int N  = in_sizes[0];
  int NT = in_sizes[6];
  int L  = in_sizes[3] / NT;   // 16
  int C  = in_sizes[1] / L;    // 1000
  int K  = in_sizes[4] / NT;   // 224
  int W  = in_sizes[5] / NT;   // 221
  int G  = in_sizes[7];        // 500
  int P  = G * L;              // 8000

  char* ws = (char*)d_ws;
  double* dpart = (double*)ws;
  int*    cnt   = (int*)(ws + 8192);
  float*  partA = (float*)(ws + 40960);
  float*  partB = (float*)(ws + 73728);
  float*  xs    = (float*)(ws + 131072);

  int SCAT = (N + 511) / 512;
  int LSEB = (NT + 255) / 256;

  hipMemsetAsync(ws, 0, 40960, stream);   // dpart + cnt
  hipLaunchKernelGGL(kB, dim3(SCAT + LSEB), dim3(256), 0, stream,
                     coords, lgi, lcg, clustering, bb, dbw, cnt, xs, dpart,
                     N, C, G, L, NT, SCAT);
  hipLaunchKernelGGL(k_pair, dim3(P), dim3(64), 0, stream,
                     uh, uw, dhw, genes_oi, xs, cnt, bb, dbw, dpart,
                     partA, partB, L, K, W, NT);
  hipLaunchKernelGGL(k_final, dim3(1), dim3(256), 0, stream,
                     partA, partB, (float*)d_out, P,
                     (long long)G * L * K + (long long)G * L);
}

// Round 8
// 59.195 us; speedup vs baseline: 5.9527x; 1.3943x over previous
//
#include <hip/hip_runtime.h>
#include <math.h>

// N=500k points, C=1000 cells, L=16 clusters, G=500 genes, NT=10000,
// K=224 heights, W=221 widths, spline levels (128,64,32).
//
// clustering one-hot => spline params depend only on (gene,cluster) pair
// (P=8000). Pipeline (round-5 structure, proven 61us):
//   kA: zero counters/dpart + per-cell cluster id (once, global 4KB table)
//   kB: scatter points into per-pair buckets + per-cluster sumexp
//   k_pair: one wave per pair builds spline table in LDS via fused scans
//           (scalar per-field arrays: conflict-light random reads), evaluates
//   k_final: single-block deterministic reduce
// Lessons: R6 - no same-address atomic tickets (8000 serialize ~290us).
//          R7 - don't rebuild cid per scatter block (+21us); compute once.

#define CAP 192       // bucket capacity (mean 62.5, max ~135)
static constexpr float  F_MBW = 1e-3f;
static constexpr float  F_MBH = 1e-3f;
static constexpr double D_HL2PI = 0.918938533204672741780329736406;

// ws layout (bytes):
//      0: double dpart[16*8]  (per-cluster sumexp, one cache line apart)
//   4096: int cid[C]
//   8192: int cnt[P]
//  40960: float partA[P]
//  73728: float partB[P]
// 131072: float xs[P*CAP]     (~6.1 MB)

// ---------------- kA: zero counters/dpart + per-cell cluster id ----------------
__global__ void __launch_bounds__(256)
kA(const float* __restrict__ clustering, int* __restrict__ cid,
   double* __restrict__ dpart, int* __restrict__ cnt, int C, int L, int P) {
  int bid = blockIdx.x, tid = threadIdx.x;
  if (bid < 4) {
    int c = bid * 256 + tid;
    if (c < C) {
      const float* row = clustering + (size_t)c * L;
      int best = 0; float bv = row[0];
      for (int l = 1; l < L; ++l) { float v = row[l]; if (v > bv) { bv = v; best = l; } }
      cid[c] = best;
    }
  } else {
    if (bid == 4 && tid < 128) dpart[tid] = 0.0;
    int i = (bid - 4) * 256 + tid;
    if (i < P) cnt[i] = 0;
  }
}

// ---------------- kB: scatter x into buckets + per-cluster sumexp ----------------
__global__ void __launch_bounds__(256)
kB(const float* __restrict__ coords, const int* __restrict__ lgi,
   const int* __restrict__ lcg, const int* __restrict__ cid,
   const float* __restrict__ bb, const float* __restrict__ dbw,
   int* __restrict__ cnt, float* __restrict__ xs, double* __restrict__ dpart,
   int N, int G, int L, int NT, int SCAT) {
  int bid = blockIdx.x;
  if (bid < SCAT) {
    int n0 = (bid * 256 + threadIdx.x) * 2;
    #pragma unroll
    for (int q = 0; q < 2; ++q) {
      int n = n0 + q;
      if (n < N) {
        int pair = lgi[n] * L + cid[lcg[n] / G];
        int pos = atomicAdd(&cnt[pair], 1);
        if (pos < CAP) xs[(size_t)pair * CAP + pos] = coords[n];
      }
    }
  } else {
    // per-cluster sum_t bb[t]*exp(dbw[t,l]); values in [8e-6,1.3] -> no max shift
    int g = (bid - SCAT) * 256 + threadIdx.x;
    float s[16];
    #pragma unroll
    for (int l = 0; l < 16; ++l) s[l] = 0.f;
    if (g < NT) {
      float b = bb[g];
      const float4* row = (const float4*)(dbw + (size_t)g * 16);
      #pragma unroll
      for (int q = 0; q < 4; ++q) {
        float4 v = row[q];
        s[4 * q + 0] = b * expf(v.x); s[4 * q + 1] = b * expf(v.y);
        s[4 * q + 2] = b * expf(v.z); s[4 * q + 3] = b * expf(v.w);
      }
    }
    __shared__ float partl[4][16];
    int lane = threadIdx.x & 63, wv = threadIdx.x >> 6;
    #pragma unroll
    for (int l = 0; l < 16; ++l) {
      float v = s[l];
      for (int off = 32; off; off >>= 1) v += __shfl_xor(v, off);
      if (lane == 0) partl[wv][l] = v;
    }
    __syncthreads();
    if (threadIdx.x < 16) {
      float t = partl[0][threadIdx.x] + partl[1][threadIdx.x]
              + partl[2][threadIdx.x] + partl[3][threadIdx.x];
      atomicAdd(&dpart[threadIdx.x * 8], (double)t);
    }
  }
}

// ---------------- wave (64-lane) inclusive scan ----------------
static __device__ __forceinline__ float wscan(float v, int lane) {
  #pragma unroll
  for (int off = 1; off < 64; off <<= 1) {
    float u = __shfl_up(v, off, 64);
    if (lane >= off) v += u;
  }
  return v;
}

// ---------------- per-pair (ONE WAVE): build table in LDS, evaluate ----------------
__global__ void __launch_bounds__(64)
k_pair(const float* __restrict__ uh, const float* __restrict__ uw,
       const float* __restrict__ dhw, const int* __restrict__ genes_oi,
       const float* __restrict__ xs, const int* __restrict__ cnt,
       const float* __restrict__ bb, const float* __restrict__ dbw,
       const double* __restrict__ dpart,
       float* __restrict__ partA, float* __restrict__ partB,
       int L, int K, int W, int NT) {
  int p = blockIdx.x;            // g*L + l
  int g = p / L;
  int cl = p - g * L;
  int gg = genes_oi[g];
  const float* uhg  = uh + (size_t)gg * K;
  const float* uwg  = uw + (size_t)gg * W;
  const float* drow = dhw + ((size_t)gg * L + cl) * K;
  int t = threadIdx.x;

  // scalar per-field arrays: random-idx 4B reads spread over all 32 banks
  __shared__ float s_loc[224];
  __shared__ float s_cdf[224];
  __shared__ float s_hh[224];
  __shared__ int   grd[224];     // uniform-grid cell -> start bin
  __shared__ float s_stg[128];   // hexp staging for neighbor access

  const float cw128 = 1.0f - F_MBW * 127.0f;
  const float chh   = 1.0f - F_MBH;
  float d2;

  // ======== level 0: nbp1=128, 2 elements per lane ========
  {
    int i0 = 2 * t, i1 = 2 * t + 1;
    float2 dv = *(const float2*)(drow + i0);
    float2 uv = *(const float2*)(uhg + i0);
    d2 = dv.x * dv.x + dv.y * dv.y;
    float hexp0 = expf(uv.x + dv.x), hexp1 = expf(uv.y + dv.y);
    s_stg[i0] = hexp0; s_stg[i1] = hexp1;
    float ew0 = expf(uwg[i0]);                    // i0 <= 126 < 127 always
    float ew1 = (i1 < 127) ? expf(uwg[i1]) : 0.f;
    float ps = wscan(ew0 + ew1, t);
    float wsum = __shfl(ps, 63);
    float incl0 = ps - ew1;
    float excl0 = incl0 - ew0, excl1 = incl0;
    float rw = cw128 / wsum;
    float width0 = F_MBW + rw * ew0;
    float width1 = F_MBW + rw * ew1;
    float loc0 = F_MBW * (float)i0 + rw * excl0;
    float loc1 = F_MBW * (float)i1 + rw * excl1;
    __syncthreads();
    float hn = (i1 < 127) ? s_stg[i1 + 1] : 0.f;
    float at0 = 0.5f * (hexp0 + hexp1) * width0;
    float at1 = (i1 < 127) ? 0.5f * (hexp1 + hn) * width1 : 0.f;
    float pa = wscan(at0 + at1, t);
    float area = __shfl(pa, 63);
    float aincl0 = pa - at1;
    float aexcl0 = aincl0 - at0, aexcl1 = aincl0;
    float ra = chh / area;
    float h0 = F_MBH + ra * hexp0, h1 = F_MBH + ra * hexp1;
    float cdf0 = F_MBH * loc0 + ra * aexcl0;
    float cdf1 = F_MBH * loc1 + ra * aexcl1;
    if (i1 == 127) { loc1 = 1.0f; cdf1 = 1.0f; }
    s_loc[i0] = loc0; s_cdf[i0] = cdf0; s_hh[i0] = h0;
    s_loc[i1] = loc1; s_cdf[i1] = cdf1; s_hh[i1] = h1;
  }

  // ======== levels 1,2: one element per lane ========
  int ho = 128, wo = 127, tb = 128;
  #pragma unroll
  for (int lev = 1; lev < 3; ++lev) {
    const int nbp1 = (lev == 1) ? 64 : 32;
    const int nb = nbp1 - 1;
    const float cwl = 1.0f - F_MBW * (float)nb;
    float dvx = (t < nbp1) ? drow[ho + t] : 0.f;
    d2 += dvx * dvx;
    float hexp = (t < nbp1) ? expf(uhg[ho + t] + dvx) : 0.f;
    __syncthreads();                 // previous level's s_stg reads done
    s_stg[t] = hexp;
    float ew = (t < nb) ? expf(uwg[wo + t]) : 0.f;
    float ips = wscan(ew, t);
    float wsum = __shfl(ips, nb - 1);
    float excl = ips - ew;
    float rw = cwl / wsum;
    float width = F_MBW + rw * ew;
    float loc = F_MBW * (float)t + rw * excl;
    __syncthreads();
    float hn = (t + 1 < nbp1) ? s_stg[t + 1] : 0.f;
    float at = (t < nb) ? 0.5f * (hexp + hn) * width : 0.f;
    float ipa = wscan(at, t);
    float area = __shfl(ipa, nb - 1);
    float aexcl = ipa - at;
    float ra = chh / area;
    float h = F_MBH + ra * hexp;
    float cdf = F_MBH * loc + ra * aexcl;
    if (t == nb) { loc = 1.0f; cdf = 1.0f; }
    if (t < nbp1) { s_loc[tb + t] = loc; s_cdf[tb + t] = cdf; s_hh[tb + t] = h; }
    ho += nbp1; wo += nb; tb += nbp1;
  }
  __syncthreads();

  // ======== uniform-grid accelerator ========
  {
    #pragma unroll
    for (int q = 0; q < 2; ++q) {     // level 0: two targets per lane
      int j = 2 * t + q;
      float target = (float)j * (1.0f / 128.0f);
      int lo = 0, hi = 128;
      #pragma unroll
      for (int it = 0; it < 7; ++it) {
        int mid = (lo + hi) >> 1;
        if (s_loc[mid] <= target) lo = mid; else hi = mid;
      }
      grd[j] = (lo > 126) ? 126 : lo;
    }
    { // level 1
      float target = (float)t * (1.0f / 64.0f);
      int lo = 0, hi = 64;
      #pragma unroll
      for (int it = 0; it < 6; ++it) {
        int mid = (lo + hi) >> 1;
        if (s_loc[128 + mid] <= target) lo = mid; else hi = mid;
      }
      grd[128 + t] = (lo > 62) ? 62 : lo;
    }
    if (t < 32) { // level 2
      float target = (float)t * (1.0f / 32.0f);
      int lo = 0, hi = 32;
      #pragma unroll
      for (int it = 0; it < 5; ++it) {
        int mid = (lo + hi) >> 1;
        if (s_loc[192 + mid] <= target) lo = mid; else hi = mid;
      }
      grd[192 + t] = (lo > 30) ? 30 : lo;
    }
  }
  __syncthreads();

  // ======== evaluate bucket ========
  int m = cnt[p]; if (m > CAP) m = CAP;
  float lad_sum = 0.f;
  for (int i = t; i < m; i += 64) {
    float x = xs[(size_t)p * CAP + i];
    float lad = 0.f;
    int b2 = 0;
    #pragma unroll
    for (int lev = 0; lev < 3; ++lev) {
      const int nbp1 = (lev == 0) ? 128 : (lev == 1) ? 64 : 32;
      int j = (int)(x * (float)nbp1);
      j = (j > nbp1 - 1) ? (nbp1 - 1) : j;
      int idx = grd[b2 + j];
      while (idx > 0 && s_loc[b2 + idx] > x) --idx;                 // fp boundary guard
      while (idx < nbp1 - 2 && s_loc[b2 + idx + 1] <= x) ++idx;     // advance (<=1 typ.)
      float la = s_loc[b2 + idx];
      float w  = s_loc[b2 + idx + 1] - la;
      float cd = s_cdf[b2 + idx];
      float hl = s_hh[b2 + idx];
      float hr = s_hh[b2 + idx + 1];
      float alpha = (x - la) / w;
      float dh = hr - hl;
      float outv = (0.5f * dh * alpha + hl) * (w * alpha) + cd;
      x = fminf(fmaxf(outv, 0.f), 1.f);
      lad += logf(alpha * dh + hl);
      b2 += nbp1;
    }
    lad_sum += lad;
  }
  // wave-only reductions
  #pragma unroll
  for (int off = 32; off; off >>= 1) {
    lad_sum += __shfl_xor(lad_sum, off);
    d2      += __shfl_xor(d2, off);
  }
  if (t == 0) {
    float dv = dbw[(size_t)gg * L + cl];
    float rc = logf(bb[gg]) + dv - logf((float)dpart[cl * 8]) + logf((float)NT);
    partA[p] = lad_sum + (float)m * rc;
    partB[p] = d2 + dv * dv;
  }
}

// ---------------- final single-block deterministic reduce ----------------
__global__ void __launch_bounds__(256)
k_final(const float* __restrict__ partA, const float* __restrict__ partB,
        float* __restrict__ out, int P, long long M12) {
  int tid = threadIdx.x;
  double sa = 0.0, sb = 0.0;
  for (int i = tid; i < P; i += 256) { sa += (double)partA[i]; sb += (double)partB[i]; }
  __shared__ double rA[256], rB[256];
  rA[tid] = sa; rB[tid] = sb;
  __syncthreads();
  for (int off = 128; off > 0; off >>= 1) {
    if (tid < off) { rA[tid] += rA[tid + off]; rB[tid] += rB[tid + off]; }
    __syncthreads();
  }
  if (tid == 0)
    out[0] = (float)(-rA[0] + 0.5 * rB[0] + (double)M12 * D_HL2PI);
}

extern "C" void kernel_launch(void* const* d_in, const int* in_sizes, int n_in,
                              void* d_out, int out_size, void* d_ws, size_t ws_size,
                              hipStream_t stream) {
  const float* coords     = (const float*)d_in[0];
  const float* clustering = (const float*)d_in[1];
  const float* dhw        = (const float*)d_in[2];
  const float* dbw        = (const float*)d_in[3];
  const float* uh         = (const float*)d_in[4];
  const float* uw         = (const float*)d_in[5];
  const float* bb         = (const float*)d_in[6];
  const int*   genes_oi   = (const int*)d_in[7];
  const int*   lgi        = (const int*)d_in[8];
  const int*   lcg        = (const int*)d_in[9];

  int N  = in_sizes[0];
  int NT = in_sizes[6];
  int L  = in_sizes[3] / NT;   // 16
  int C  = in_sizes[1] / L;    // 1000
  int K  = in_sizes[4] / NT;   // 224
  int W  = in_sizes[5] / NT;   // 221
  int G  = in_sizes[7];        // 500
  int P  = G * L;              // 8000

  char* ws = (char*)d_ws;
  double* dpart = (double*)ws;
  int*    cid   = (int*)(ws + 4096);
  int*    cnt   = (int*)(ws + 8192);
  float*  partA = (float*)(ws + 40960);
  float*  partB = (float*)(ws + 73728);
  float*  xs    = (float*)(ws + 131072);

  int SCAT = (N + 511) / 512;
  int LSEB = (NT + 255) / 256;

  hipLaunchKernelGGL(kA, dim3(4 + (P + 255) / 256), dim3(256), 0, stream,
                     clustering, cid, dpart, cnt, C, L, P);
  hipLaunchKernelGGL(kB, dim3(SCAT + LSEB), dim3(256), 0, stream,
                     coords, lgi, lcg, cid, bb, dbw, cnt, xs, dpart,
                     N, G, L, NT, SCAT);
  hipLaunchKernelGGL(k_pair, dim3(P), dim3(64), 0, stream,
                     uh, uw, dhw, genes_oi, xs, cnt, bb, dbw, dpart,
                     partA, partB, L, K, W, NT);
  hipLaunchKernelGGL(k_final, dim3(1), dim3(256), 0, stream,
                     partA, partB, (float*)d_out, P,
                     (long long)G * L * K + (long long)G * L);
}

// Round 9
// 55.411 us; speedup vs baseline: 6.3592x; 1.0683x over previous
//
#include <hip/hip_runtime.h>
#include <math.h>

// N=500k points, C=1000 cells, L=16 clusters, G=500 genes, NT=10000,
// K=224 heights, W=221 widths, spline levels (128,64,32).
//
// clustering one-hot => spline params depend only on (gene,cluster) pair
// (P=8000). Pipeline:
//   kA: zero counters/dpart + per-cell cluster id (once, global 4KB table)
//   kB: scatter points into per-pair buckets + per-cluster sumexp
//   k_pair: one wave per pair builds spline table in LDS via THREE PARALLEL
//           wave-scans (ew, a=0.5(h_i+h_{i+1}), b=a*ew; neighbors via shfl,
//           no LDS staging), then evaluates bucket via uniform-grid lookup
//   k_final: single-block (1024t) deterministic reduce
// Lessons: R6 - no same-address atomic tickets (8000 serialize ~290us).
//          R7 - don't rebuild cid per scatter block (+21us); compute once.

#define CAP 192       // bucket capacity (mean 62.5, max ~135)
static constexpr float  F_MBW = 1e-3f;
static constexpr float  F_MBH = 1e-3f;
static constexpr double D_HL2PI = 0.918938533204672741780329736406;

// ws layout (bytes):
//      0: double dpart[16*8]  (per-cluster sumexp, one cache line apart)
//   4096: int cid[C]
//   8192: int cnt[P]
//  40960: float partA[P]
//  73728: float partB[P]
// 131072: float xs[P*CAP]     (~6.1 MB)

// ---------------- kA: zero counters/dpart + per-cell cluster id ----------------
__global__ void __launch_bounds__(256)
kA(const float* __restrict__ clustering, int* __restrict__ cid,
   double* __restrict__ dpart, int* __restrict__ cnt, int C, int L, int P) {
  int bid = blockIdx.x, tid = threadIdx.x;
  if (bid < 4) {
    int c = bid * 256 + tid;
    if (c < C) {
      const float* row = clustering + (size_t)c * L;
      int best = 0; float bv = row[0];
      for (int l = 1; l < L; ++l) { float v = row[l]; if (v > bv) { bv = v; best = l; } }
      cid[c] = best;
    }
  } else {
    if (bid == 4 && tid < 128) dpart[tid] = 0.0;
    int i = (bid - 4) * 256 + tid;
    if (i < P) cnt[i] = 0;
  }
}

// ---------------- kB: scatter x into buckets + per-cluster sumexp ----------------
__global__ void __launch_bounds__(256)
kB(const float* __restrict__ coords, const int* __restrict__ lgi,
   const int* __restrict__ lcg, const int* __restrict__ cid,
   const float* __restrict__ bb, const float* __restrict__ dbw,
   int* __restrict__ cnt, float* __restrict__ xs, double* __restrict__ dpart,
   int N, int G, int L, int NT, int SCAT) {
  int bid = blockIdx.x;
  if (bid < SCAT) {
    int base = bid * 512;
    #pragma unroll
    for (int q = 0; q < 2; ++q) {       // two fully-coalesced 256-wide sweeps
      int n = base + q * 256 + threadIdx.x;
      if (n < N) {
        int pair = lgi[n] * L + cid[lcg[n] / G];
        int pos = atomicAdd(&cnt[pair], 1);
        if (pos < CAP) xs[(size_t)pair * CAP + pos] = coords[n];
      }
    }
  } else {
    // per-cluster sum_t bb[t]*exp(dbw[t,l]); values in [8e-6,1.3] -> no max shift
    int g = (bid - SCAT) * 256 + threadIdx.x;
    float s[16];
    #pragma unroll
    for (int l = 0; l < 16; ++l) s[l] = 0.f;
    if (g < NT) {
      float b = bb[g];
      const float4* row = (const float4*)(dbw + (size_t)g * 16);
      #pragma unroll
      for (int q = 0; q < 4; ++q) {
        float4 v = row[q];
        s[4 * q + 0] = b * expf(v.x); s[4 * q + 1] = b * expf(v.y);
        s[4 * q + 2] = b * expf(v.z); s[4 * q + 3] = b * expf(v.w);
      }
    }
    __shared__ float partl[4][16];
    int lane = threadIdx.x & 63, wv = threadIdx.x >> 6;
    #pragma unroll
    for (int l = 0; l < 16; ++l) {
      float v = s[l];
      for (int off = 32; off; off >>= 1) v += __shfl_xor(v, off);
      if (lane == 0) partl[wv][l] = v;
    }
    __syncthreads();
    if (threadIdx.x < 16) {
      float t = partl[0][threadIdx.x] + partl[1][threadIdx.x]
              + partl[2][threadIdx.x] + partl[3][threadIdx.x];
      atomicAdd(&dpart[threadIdx.x * 8], (double)t);
    }
  }
}

// ---------------- three independent wave scans in lock-step ----------------
static __device__ __forceinline__ void wscan3(float& x, float& y, float& z, int lane) {
  #pragma unroll
  for (int off = 1; off < 64; off <<= 1) {
    float a = __shfl_up(x, off, 64);
    float b = __shfl_up(y, off, 64);
    float c = __shfl_up(z, off, 64);
    if (lane >= off) { x += a; y += b; z += c; }
  }
}

// ---------------- per-pair (ONE WAVE): build table in LDS, evaluate ----------------
__global__ void __launch_bounds__(64)
k_pair(const float* __restrict__ uh, const float* __restrict__ uw,
       const float* __restrict__ dhw, const int* __restrict__ genes_oi,
       const float* __restrict__ xs, const int* __restrict__ cnt,
       const float* __restrict__ bb, const float* __restrict__ dbw,
       const double* __restrict__ dpart,
       float* __restrict__ partA, float* __restrict__ partB,
       int L, int K, int W, int NT) {
  int p = blockIdx.x;            // g*L + l
  int g = p / L;
  int cl = p - g * L;
  int gg = genes_oi[g];
  const float* uhg  = uh + (size_t)gg * K;
  const float* uwg  = uw + (size_t)gg * W;
  const float* drow = dhw + ((size_t)gg * L + cl) * K;
  int t = threadIdx.x;

  // scalar per-field arrays: random-idx 4B reads spread over all 32 banks
  __shared__ float s_loc[224];
  __shared__ float s_cdf[224];
  __shared__ float s_hh[224];
  __shared__ int   grd[224];     // uniform-grid cell -> start bin

  const float chh = 1.0f - F_MBH;
  float d2;

  // ======== level 0: nbp1=128, 2 elements per lane ========
  {
    const float cw128 = 1.0f - F_MBW * 127.0f;
    int i0 = 2 * t, i1 = 2 * t + 1;
    float2 dv = *(const float2*)(drow + i0);
    float2 uv = *(const float2*)(uhg + i0);
    d2 = dv.x * dv.x + dv.y * dv.y;
    float h0 = expf(uv.x + dv.x), h1 = expf(uv.y + dv.y);
    float h2 = __shfl_down(h0, 1, 64);            // next lane's h0 (t=63: unused)
    float ew0 = expf(uwg[i0]);                    // i0 <= 126 always
    float ew1 = (i1 < 127) ? expf(uwg[i1]) : 0.f;
    float a0 = 0.5f * (h0 + h1);
    float a1 = (i1 < 127) ? 0.5f * (h1 + h2) : 0.f;
    float b0 = a0 * ew0, b1 = a1 * ew1;
    float sew = ew0 + ew1, sa = a0 + a1, sb = b0 + b1;
    wscan3(sew, sa, sb, t);
    float wsum = __shfl(sew, 63);
    float S1   = __shfl(sa, 63);
    float S2   = __shfl(sb, 63);
    float rw = cw128 / wsum;
    float area = F_MBW * S1 + rw * S2;
    float ra = chh / area;
    // exclusive prefixes per element
    float E0 = sew - (ew0 + ew1), E1 = E0 + ew0;
    float A0 = sa - (a0 + a1),    A1 = A0 + a0;
    float B0 = sb - (b0 + b1),    B1 = B0 + b0;
    float loc0 = F_MBW * (float)i0 + rw * E0;
    float loc1 = F_MBW * (float)i1 + rw * E1;
    float cdf0 = F_MBH * loc0 + ra * (F_MBW * A0 + rw * B0);
    float cdf1 = F_MBH * loc1 + ra * (F_MBW * A1 + rw * B1);
    if (i1 == 127) { loc1 = 1.0f; cdf1 = 1.0f; }
    s_loc[i0] = loc0; s_cdf[i0] = cdf0; s_hh[i0] = F_MBH + ra * h0;
    s_loc[i1] = loc1; s_cdf[i1] = cdf1; s_hh[i1] = F_MBH + ra * h1;
  }

  // ======== levels 1,2: one element per lane ========
  int ho = 128, wo = 127, tb = 128;
  #pragma unroll
  for (int lev = 1; lev < 3; ++lev) {
    const int nbp1 = (lev == 1) ? 64 : 32;
    const int nb = nbp1 - 1;
    const float cwl = 1.0f - F_MBW * (float)nb;
    float dvx = (t < nbp1) ? drow[ho + t] : 0.f;
    d2 += dvx * dvx;
    float hexp = (t < nbp1) ? expf(uhg[ho + t] + dvx) : 0.f;
    float hn = __shfl_down(hexp, 1, 64);          // h_{i+1} (t=nb: unused)
    float ew = (t < nb) ? expf(uwg[wo + t]) : 0.f;
    float a  = (t < nb) ? 0.5f * (hexp + hn) : 0.f;
    float b  = a * ew;
    float sew = ew, sa = a, sb = b;
    wscan3(sew, sa, sb, t);
    float wsum = __shfl(sew, 63);
    float S1   = __shfl(sa, 63);
    float S2   = __shfl(sb, 63);
    float rw = cwl / wsum;
    float area = F_MBW * S1 + rw * S2;
    float ra = chh / area;
    float E = sew - ew, A = sa - a, B = sb - b;
    float loc = F_MBW * (float)t + rw * E;
    float cdf = F_MBH * loc + ra * (F_MBW * A + rw * B);
    float h = F_MBH + ra * hexp;
    if (t == nb) { loc = 1.0f; cdf = 1.0f; }
    if (t < nbp1) { s_loc[tb + t] = loc; s_cdf[tb + t] = cdf; s_hh[tb + t] = h; }
    ho += nbp1; wo += nb; tb += nbp1;
  }
  __syncthreads();

  // ======== uniform-grid accelerator ========
  {
    #pragma unroll
    for (int q = 0; q < 2; ++q) {     // level 0: two targets per lane
      int j = 2 * t + q;
      float target = (float)j * (1.0f / 128.0f);
      int lo = 0, hi = 128;
      #pragma unroll
      for (int it = 0; it < 7; ++it) {
        int mid = (lo + hi) >> 1;
        if (s_loc[mid] <= target) lo = mid; else hi = mid;
      }
      grd[j] = (lo > 126) ? 126 : lo;
    }
    { // level 1
      float target = (float)t * (1.0f / 64.0f);
      int lo = 0, hi = 64;
      #pragma unroll
      for (int it = 0; it < 6; ++it) {
        int mid = (lo + hi) >> 1;
        if (s_loc[128 + mid] <= target) lo = mid; else hi = mid;
      }
      grd[128 + t] = (lo > 62) ? 62 : lo;
    }
    if (t < 32) { // level 2
      float target = (float)t * (1.0f / 32.0f);
      int lo = 0, hi = 32;
      #pragma unroll
      for (int it = 0; it < 5; ++it) {
        int mid = (lo + hi) >> 1;
        if (s_loc[192 + mid] <= target) lo = mid; else hi = mid;
      }
      grd[192 + t] = (lo > 30) ? 30 : lo;
    }
  }
  __syncthreads();

  // ======== evaluate bucket ========
  int m = cnt[p]; if (m > CAP) m = CAP;
  float lad_sum = 0.f;
  for (int i = t; i < m; i += 64) {
    float x = xs[(size_t)p * CAP + i];
    float lad = 0.f;
    int b2 = 0;
    #pragma unroll
    for (int lev = 0; lev < 3; ++lev) {
      const int nbp1 = (lev == 0) ? 128 : (lev == 1) ? 64 : 32;
      int j = (int)(x * (float)nbp1);
      j = (j > nbp1 - 1) ? (nbp1 - 1) : j;
      int idx = grd[b2 + j];
      while (idx > 0 && s_loc[b2 + idx] > x) --idx;                 // fp boundary guard
      while (idx < nbp1 - 2 && s_loc[b2 + idx + 1] <= x) ++idx;     // advance (<=1 typ.)
      float la = s_loc[b2 + idx];
      float w  = s_loc[b2 + idx + 1] - la;
      float cd = s_cdf[b2 + idx];
      float hl = s_hh[b2 + idx];
      float hr = s_hh[b2 + idx + 1];
      float alpha = (x - la) / w;
      float dh = hr - hl;
      float outv = (0.5f * dh * alpha + hl) * (w * alpha) + cd;
      x = fminf(fmaxf(outv, 0.f), 1.f);
      lad += logf(alpha * dh + hl);
      b2 += nbp1;
    }
    lad_sum += lad;
  }
  // wave-only reductions
  #pragma unroll
  for (int off = 32; off; off >>= 1) {
    lad_sum += __shfl_xor(lad_sum, off);
    d2      += __shfl_xor(d2, off);
  }
  if (t == 0) {
    float dv = dbw[(size_t)gg * L + cl];
    float rc = logf(bb[gg]) + dv - logf((float)dpart[cl * 8]) + logf((float)NT);
    partA[p] = lad_sum + (float)m * rc;
    partB[p] = d2 + dv * dv;
  }
}

// ---------------- final single-block deterministic reduce (1024t) ----------------
__global__ void __launch_bounds__(1024)
k_final(const float* __restrict__ partA, const float* __restrict__ partB,
        float* __restrict__ out, int P, long long M12) {
  int tid = threadIdx.x;
  double sa = 0.0, sb = 0.0;
  for (int i = tid; i < P; i += 1024) { sa += (double)partA[i]; sb += (double)partB[i]; }
  __shared__ double rA[1024], rB[1024];
  rA[tid] = sa; rB[tid] = sb;
  __syncthreads();
  for (int off = 512; off > 0; off >>= 1) {
    if (tid < off) { rA[tid] += rA[tid + off]; rB[tid] += rB[tid + off]; }
    __syncthreads();
  }
  if (tid == 0)
    out[0] = (float)(-rA[0] + 0.5 * rB[0] + (double)M12 * D_HL2PI);
}

extern "C" void kernel_launch(void* const* d_in, const int* in_sizes, int n_in,
                              void* d_out, int out_size, void* d_ws, size_t ws_size,
                              hipStream_t stream) {
  const float* coords     = (const float*)d_in[0];
  const float* clustering = (const float*)d_in[1];
  const float* dhw        = (const float*)d_in[2];
  const float* dbw        = (const float*)d_in[3];
  const float* uh         = (const float*)d_in[4];
  const float* uw         = (const float*)d_in[5];
  const float* bb         = (const float*)d_in[6];
  const int*   genes_oi   = (const int*)d_in[7];
  const int*   lgi        = (const int*)d_in[8];
  const int*   lcg        = (const int*)d_in[9];

  int N  = in_sizes[0];
  int NT = in_sizes[6];
  int L  = in_sizes[3] / NT;   // 16
  int C  = in_sizes[1] / L;    // 1000
  int K  = in_sizes[4] / NT;   // 224
  int W  = in_sizes[5] / NT;   // 221
  int G  = in_sizes[7];        // 500
  int P  = G * L;              // 8000

  char* ws = (char*)d_ws;
  double* dpart = (double*)ws;
  int*    cid   = (int*)(ws + 4096);
  int*    cnt   = (int*)(ws + 8192);
  float*  partA = (float*)(ws + 40960);
  float*  partB = (float*)(ws + 73728);
  float*  xs    = (float*)(ws + 131072);

  int SCAT = (N + 511) / 512;
  int LSEB = (NT + 255) / 256;

  hipLaunchKernelGGL(kA, dim3(4 + (P + 255) / 256), dim3(256), 0, stream,
                     clustering, cid, dpart, cnt, C, L, P);
  hipLaunchKernelGGL(kB, dim3(SCAT + LSEB), dim3(256), 0, stream,
                     coords, lgi, lcg, cid, bb, dbw, cnt, xs, dpart,
                     N, G, L, NT, SCAT);
  hipLaunchKernelGGL(k_pair, dim3(P), dim3(64), 0, stream,
                     uh, uw, dhw, genes_oi, xs, cnt, bb, dbw, dpart,
                     partA, partB, L, K, W, NT);
  hipLaunchKernelGGL(k_final, dim3(1), dim3(1024), 0, stream,
                     partA, partB, (float*)d_out, P,
                     (long long)G * L * K + (long long)G * L);
}